// Round 3
// baseline (443.342 us; speedup 1.0000x reference)
//
#include <hip/hip_runtime.h>
#include <math.h>

#define EPSF 1e-12f

// N=64, C=512, P=1600, K=64
// R6: fused pipeline (3 dispatches).
//   k0 : Wb[k][c] = bf16(W); zeros asum.
//   kf : FUSED GEMM1+softmax+GEMM2. Grid (5 p-chunks of 320, 64 n), 512 thr.
//        Per 64-p subtile: [all 8 waves: stage x fp32->regs (c-halves), ss,
//        partial logits MFMA, bf16 x-tile -> LDS] bar [waves 0-3: combine
//        halves, softmax (R1/R3-verified code), a' -> LDS abuf] bar
//        [all 8 waves: GEMM2 K=64 from LDS, acc in regs] bar.
//        x read ONCE (210 MB vs 420); a_t global round-trip eliminated.
//        Output: per-chunk partial slabs part[5][n][64k][512c] (no atomics).
//   k4 : merged epilogue per n: sum 5 partials, rownorm2, gn, final normalize;
//        vlad rows staged in LDS (131 KB). One dispatch, no rn2/gn globals.
// ws: part @0 (41,943,040) | Wb @41,943,040 (65,536) | asum @42,008,576

typedef short bf16x8 __attribute__((ext_vector_type(8)));
typedef float f32x4  __attribute__((ext_vector_type(4)));

__device__ __forceinline__ ushort f2b(float x) {
    unsigned u = __float_as_uint(x);
    return (ushort)((u + 0x7fffu + ((u >> 16) & 1u)) >> 16);
}

// ------------------------------------------------- K0: Wb[k][c] = bf16(W), asum=0
__global__ __launch_bounds__(256) void k0_wb(const float* __restrict__ W,
                                             ushort* __restrict__ Wb,
                                             float* __restrict__ asum) {
    int i = blockIdx.x * 256 + threadIdx.x;
    if (i < 64 * 512) Wb[i] = f2b(W[i]);
    if (i < 64 * 64) asum[i] = 0.f;
}

// ------------------------------------------------- KF: fused GEMM1+softmax+GEMM2
// LDS: xs[512 c][72] bf16 (64-p subtile, pad-72 rows: stride 144B = 36 dw -> 2-way
// free banks on b128); abuf[64 k][72] bf16; accb f32 logit-half exchange; ssb.
__global__ __launch_bounds__(512, 2) void kf(const float* __restrict__ x,
                                             const ushort* __restrict__ Wb,
                                             float* __restrict__ part,
                                             float* __restrict__ asum) {
    const int cb = blockIdx.x;           // p-chunk 0..4 (320 p each)
    const int n  = blockIdx.y;
    const int wv = threadIdx.x >> 6, lane = threadIdx.x & 63;
    const int q = lane >> 4, l15 = lane & 15;
    const int pt = wv & 3, ch = wv >> 2; // p-tile 0..3, c-half 0..1
    const int cw = wv * 64;              // GEMM2 c-range per wave

    __shared__ ushort xs[512 * 72];
    __shared__ ushort abuf[64 * 72];
    __shared__ float  accb[4 * 4 * 64 * 4];  // [pt][nt][lane][4]
    __shared__ float  ssb[2 * 4 * 16];       // [ch][pt][l15]

    f32x4 acc2[4][4] = {};               // GEMM2 acc: [k-mt][c-nt], lives all subtiles

    const ushort* wrow = Wb + l15 * 512 + ch * 256 + q * 8;

    for (int s = 0; s < 5; s++) {
        // ---------- phase 1: stage + GEMM1 partial (all waves), c-half = ch
        const float* xq = x + (size_t)n * 819200 + (size_t)(ch * 256 + q * 8) * 1600
                            + (size_t)cb * 320 + s * 64 + pt * 16 + l15;
        f32x4 acc1[4] = {};
        float ssp = 0.f;
        float fv[2][8];
        #pragma unroll
        for (int j = 0; j < 8; j++) fv[0][j] = xq[(size_t)j * 1600];
        #pragma unroll
        for (int kc = 0; kc < 8; kc++) {
            const int cur = kc & 1, nxt = cur ^ 1;
            if (kc < 7) {
                #pragma unroll
                for (int j = 0; j < 8; j++)
                    fv[nxt][j] = xq[(size_t)((kc + 1) * 32 + j) * 1600];
            }
            bf16x8 af;
            #pragma unroll
            for (int j = 0; j < 8; j++) {
                float f = fv[cur][j];
                ssp = fmaf(f, f, ssp);          // fp32-accurate sum of squares
                ushort b = f2b(f);
                af[j] = (short)b;
                xs[(ch * 256 + kc * 32 + q * 8 + j) * 72 + pt * 16 + l15] = b;
            }
            #pragma unroll
            for (int nt = 0; nt < 4; nt++) {
                bf16x8 bw = *(const bf16x8*)(wrow + nt * 16 * 512 + kc * 32);
                acc1[nt] = __builtin_amdgcn_mfma_f32_16x16x32_bf16(af, bw, acc1[nt], 0, 0, 0);
            }
        }
        // ss over this wave's q-groups (covers its 256-c half)
        ssp += __shfl_xor(ssp, 16, 64);
        ssp += __shfl_xor(ssp, 32, 64);
        if (lane < 16) ssb[ch * 64 + pt * 16 + lane] = ssp;
        if (ch == 1) {
            #pragma unroll
            for (int nt = 0; nt < 4; nt++)
                *(f32x4*)&accb[((pt * 4 + nt) * 64 + lane) * 4] = acc1[nt];
        }
        __syncthreads();  // accb/ssb/xs(s) visible

        // ---------- phase 2: combine halves + softmax + a' (waves 0-3)
        if (ch == 0) {
            #pragma unroll
            for (int nt = 0; nt < 4; nt++)
                acc1[nt] += *(const f32x4*)&accb[((pt * 4 + nt) * 64 + lane) * 4];
            float sst = ssb[pt * 16 + l15] + ssb[64 + pt * 16 + l15];
            float rn_l = 1.f / fmaxf(sqrtf(sst), EPSF);
            float rnv[4];
            #pragma unroll
            for (int r = 0; r < 4; r++) rnv[r] = __shfl(rn_l, q * 4 + r, 64);

            // softmax over k (4 nt in-lane x 16 l15 cross-lane)  [R1/R3-verified]
            float v[4][4];
            float mx[4] = {-3.4e38f, -3.4e38f, -3.4e38f, -3.4e38f};
            #pragma unroll
            for (int nt = 0; nt < 4; nt++)
                #pragma unroll
                for (int r = 0; r < 4; r++) {
                    v[nt][r] = acc1[nt][r] * rnv[r];
                    mx[r] = fmaxf(mx[r], v[nt][r]);
                }
            #pragma unroll
            for (int sh = 1; sh <= 8; sh <<= 1)
                #pragma unroll
                for (int r = 0; r < 4; r++) mx[r] = fmaxf(mx[r], __shfl_xor(mx[r], sh, 64));
            float sm[4] = {0.f, 0.f, 0.f, 0.f};
            #pragma unroll
            for (int nt = 0; nt < 4; nt++)
                #pragma unroll
                for (int r = 0; r < 4; r++) { v[nt][r] = __expf(v[nt][r] - mx[r]); sm[r] += v[nt][r]; }
            #pragma unroll
            for (int sh = 1; sh <= 8; sh <<= 1)
                #pragma unroll
                for (int r = 0; r < 4; r++) sm[r] += __shfl_xor(sm[r], sh, 64);
            float inv[4];
            #pragma unroll
            for (int r = 0; r < 4; r++) inv[r] = 1.f / sm[r];
            #pragma unroll
            for (int nt = 0; nt < 4; nt++)
                #pragma unroll
                for (int r = 0; r < 4; r++) v[nt][r] *= inv[r];

            // asum partials (sum of a over this wave's 16 p)
            #pragma unroll
            for (int nt = 0; nt < 4; nt++) {
                float t = v[nt][0] + v[nt][1] + v[nt][2] + v[nt][3];
                t += __shfl_xor(t, 16, 64);
                t += __shfl_xor(t, 32, 64);
                if (lane < 16) atomicAdd(&asum[n * 64 + nt * 16 + lane], t);
            }

            // a' = a*rn -> bf16 into abuf[k][72] (4 consecutive p packed)
            #pragma unroll
            for (int nt = 0; nt < 4; nt++) {
                ushort4 pk;
                pk.x = f2b(v[nt][0] * rnv[0]);
                pk.y = f2b(v[nt][1] * rnv[1]);
                pk.z = f2b(v[nt][2] * rnv[2]);
                pk.w = f2b(v[nt][3] * rnv[3]);
                *(ushort4*)&abuf[(nt * 16 + l15) * 72 + pt * 16 + q * 4] = pk;
            }
        }
        __syncthreads();  // abuf visible

        // ---------- phase 3: GEMM2 K=64 from LDS (all waves)  [k3g frag mapping]
        #pragma unroll
        for (int ks = 0; ks < 2; ks++) {
            bf16x8 av[4];
            #pragma unroll
            for (int mt = 0; mt < 4; mt++)
                av[mt] = *(const bf16x8*)&abuf[(mt * 16 + l15) * 72 + ks * 32 + q * 8];
            bf16x8 bv[4];
            #pragma unroll
            for (int nt = 0; nt < 4; nt++)
                bv[nt] = *(const bf16x8*)&xs[(cw + nt * 16 + l15) * 72 + ks * 32 + q * 8];
            #pragma unroll
            for (int mt = 0; mt < 4; mt++)
                #pragma unroll
                for (int nt = 0; nt < 4; nt++)
                    acc2[mt][nt] = __builtin_amdgcn_mfma_f32_16x16x32_bf16(av[mt], bv[nt], acc2[mt][nt], 0, 0, 0);
        }
        __syncthreads();  // xs/abuf free for next subtile
    }

    // partial slab store: part[cb][n][k][c], sole owner -> plain stores
    float* ob = part + ((size_t)cb * 64 + n) * 32768 + cw + l15;
    #pragma unroll
    for (int mt = 0; mt < 4; mt++)
        #pragma unroll
        for (int nt = 0; nt < 4; nt++)
            #pragma unroll
            for (int r = 0; r < 4; r++)
                ob[(mt * 16 + q * 4 + r) * 512 + nt * 16] = acc2[mt][nt][r];
}

// ------------------------------------------------- K4: merged epilogue per n
// sum 5 partials -> vlad rows in LDS -> rownorm2 -> gn -> normalize -> out.
__global__ __launch_bounds__(512) void k4(const float* __restrict__ part,
                                          const float* __restrict__ asum,
                                          const float* __restrict__ cent,
                                          float* __restrict__ out) {
    const int n = blockIdx.x;
    const int wv = threadIdx.x >> 6, lane = threadIdx.x & 63;
    __shared__ float stash[64 * 512];
    __shared__ float rs[64];
    __shared__ float gsh;

    #pragma unroll
    for (int i = 0; i < 8; i++) {
        const int k = wv * 8 + i;
        const size_t ro = (size_t)n * 32768 + (size_t)k * 512 + lane * 8;
        const float as = asum[n * 64 + k];
        f32x4 a0 = {}, a1 = {};
        #pragma unroll
        for (int cbk = 0; cbk < 5; cbk++) {
            const f32x4* pp = (const f32x4*)(part + (size_t)cbk * 2097152 + ro);
            a0 += pp[0];
            a1 += pp[1];
        }
        const f32x4* cp = (const f32x4*)(cent + k * 512 + lane * 8);
        f32x4 v0 = a0 - cp[0] * as;
        f32x4 v1 = a1 - cp[1] * as;
        float s = 0.f;
        #pragma unroll
        for (int e = 0; e < 4; e++) { s = fmaf(v0[e], v0[e], s); s = fmaf(v1[e], v1[e], s); }
        *(f32x4*)&stash[k * 512 + lane * 8] = v0;
        *(f32x4*)&stash[k * 512 + lane * 8 + 4] = v1;
        #pragma unroll
        for (int off = 32; off > 0; off >>= 1) s += __shfl_down(s, off, 64);
        if (lane == 0) rs[k] = s;
    }
    __syncthreads();
    if (wv == 0) {
        float t = rs[lane];
        float d = fmaxf(sqrtf(t), EPSF);
        float r = t / (d * d);
        #pragma unroll
        for (int off = 32; off > 0; off >>= 1) r += __shfl_down(r, off, 64);
        if (lane == 0) gsh = fmaxf(sqrtf(r), EPSF);
    }
    __syncthreads();
    const float g = gsh;
    #pragma unroll
    for (int i = 0; i < 8; i++) {
        const int k = wv * 8 + i;
        const float inv = 1.f / (fmaxf(sqrtf(rs[k]), EPSF) * g);
        f32x4 v0 = *(const f32x4*)&stash[k * 512 + lane * 8];
        f32x4 v1 = *(const f32x4*)&stash[k * 512 + lane * 8 + 4];
        v0 *= inv;
        v1 *= inv;
        float* op = out + (size_t)n * 32768 + (size_t)k * 512 + lane * 8;
        *(f32x4*)op = v0;
        *(f32x4*)(op + 4) = v1;
    }
}

// -------------------------------------------------
extern "C" void kernel_launch(void* const* d_in, const int* in_sizes, int n_in,
                              void* d_out, int out_size, void* d_ws, size_t ws_size,
                              hipStream_t stream) {
    const float* x    = (const float*)d_in[0];
    const float* W    = (const float*)d_in[1];
    const float* cent = (const float*)d_in[2];
    float* out = (float*)d_out;
    char* ws = (char*)d_ws;

    float*  part = (float*)(ws + 0);            // 5 * 64 * 32768 * 4 = 41,943,040
    ushort* Wb   = (ushort*)(ws + 41943040);    // 65,536
    float*  asum = (float*)(ws + 42008576);     // 16,384

    hipLaunchKernelGGL(k0_wb, dim3(128),   dim3(256), 0, stream, W, Wb, asum);
    hipLaunchKernelGGL(kf,    dim3(5, 64), dim3(512), 0, stream, x, Wb, part, asum);
    hipLaunchKernelGGL(k4,    dim3(64),    dim3(512), 0, stream, part, asum, cent, out);
}